// Round 1
// baseline (400.337 us; speedup 1.0000x reference)
//
#include <hip/hip_runtime.h>
#include <stdint.h>

// FusedGCNLayer: out = segment_sum(vals * (x @ W^T)[col], row)
// N=65536, E=524288, F=EMB=512.
// Pipeline: (0) convert w fp32->bf16 (tiny)
//           (1) gemm_fused: BM=64 x BN=512 blocks, reg-staged fp32->bf16 A + GLDS B.
//               x is read EXACTLY ONCE from HBM (no separate conv pass for x).
//           (2) bin edges by dest row (packed 8B)
//           (3) rowsum: one wave per TWO rows (MLP probe), gather-accumulate, NT out stores.

#define N_NODES 65536
#define N_EDGES 524288
#define FEAT    512
#define EMB     512
#define CAP     64

typedef short  short8  __attribute__((ext_vector_type(8)));
typedef float  floatx4 __attribute__((ext_vector_type(4)));
typedef unsigned int uintx2 __attribute__((ext_vector_type(2)));

__device__ __forceinline__ unsigned short f2bf(float f) {
    unsigned int u = __float_as_uint(f);
    u += 0x7FFFu + ((u >> 16) & 1u);   // RNE
    return (unsigned short)(u >> 16);
}
__device__ __forceinline__ float bf2f_lo(unsigned int u){ return __uint_as_float(u << 16); }
__device__ __forceinline__ float bf2f_hi(unsigned int u){ return __uint_as_float(u & 0xffff0000u); }

typedef __attribute__((address_space(1))) const void* gas_vp;
typedef __attribute__((address_space(3))) void*       las_vp;
#define GLDS16(g, l) __builtin_amdgcn_global_load_lds((gas_vp)(const void*)(g), (las_vp)(void*)(l), 16, 0, 0)

// ---------------- fp32 -> bf16 convert (used for w only on fast path) ----------------
__global__ __launch_bounds__(256)
void conv_bf16(const float* __restrict__ in, unsigned short* __restrict__ out)
{
    size_t i = ((size_t)blockIdx.x * 256 + threadIdx.x) * 8;
    floatx4 a = __builtin_nontemporal_load((const floatx4*)&in[i]);
    floatx4 b = __builtin_nontemporal_load((const floatx4*)&in[i + 4]);
    ushort4 lo, hi;
    lo.x = f2bf(a.x); lo.y = f2bf(a.y); lo.z = f2bf(a.z); lo.w = f2bf(a.w);
    hi.x = f2bf(b.x); hi.y = f2bf(b.y); hi.z = f2bf(b.z); hi.w = f2bf(b.w);
    *(ushort4*)&out[i]     = lo;
    *(ushort4*)&out[i + 4] = hi;
}

// ---------------- fused GEMM: BM=64 x BN=512, x read once, in-register convert ----------------
// 512 threads = 8 waves; wave w owns output cols [w*64, w*64+64).
// A (x tile): fp32 global -> regs -> f2bf -> swizzled ds_write_b128 (issue-early prefetch).
// B (wb):     global_load_lds width-16, pre-swizzled source, linear LDS dest.
__global__ __launch_bounds__(512, 4)
void gemm_fused(const float* __restrict__ x, const unsigned short* __restrict__ wb,
                unsigned short* __restrict__ h)
{
    __shared__ unsigned short As[64 * 64];    //  8 KB
    __shared__ unsigned short Bs[512 * 64];   // 64 KB

    const int t    = threadIdx.x;      // 0..511
    const int lane = t & 63;
    const int wave = t >> 6;           // 0..7 -> n-block
    const int l15  = lane & 15;
    const int lq   = lane >> 4;

    const int m0 = blockIdx.x * 64;

    const int r8 = t >> 3;             // 0..63 (A row / staging row)
    const int c8 = t & 7;              // 16B chunk index

    floatx4 acc[4][4];
    #pragma unroll
    for (int i = 0; i < 4; i++)
        #pragma unroll
        for (int j = 0; j < 4; j++) acc[i][j] = (floatx4){0.f, 0.f, 0.f, 0.f};

    // prefetch K-step 0 of A into regs
    float4 xa, xb_;
    {
        const float* px = &x[(size_t)(m0 + r8) * FEAT + c8 * 8];
        xa  = *(const float4*)px;
        xb_ = *(const float4*)(px + 4);
    }

    for (int kb = 0; kb < FEAT; kb += 64) {
        // stage Bs: all 512 w-rows, 64-wide K slab, pre-swizzled global source
        #pragma unroll
        for (int p = 0; p < 8; p++) {
            int row = p * 64 + r8;
            int lc  = c8 ^ (r8 & 7);                 // row&7 == r8&7 (p*64 % 8 == 0)
            GLDS16(&wb[row * FEAT + kb + lc * 8], &Bs[row * 64 + c8 * 8]);
        }
        // convert prefetched A regs -> swizzled LDS write (logical chunk c8 at phys c8^(r8&7))
        {
            short8 v;
            v[0] = (short)f2bf(xa.x);  v[1] = (short)f2bf(xa.y);
            v[2] = (short)f2bf(xa.z);  v[3] = (short)f2bf(xa.w);
            v[4] = (short)f2bf(xb_.x); v[5] = (short)f2bf(xb_.y);
            v[6] = (short)f2bf(xb_.z); v[7] = (short)f2bf(xb_.w);
            *(short8*)&As[r8 * 64 + (c8 ^ (r8 & 7)) * 8] = v;
        }
        __syncthreads();

        // issue next K-step's x loads; latency hides under MFMA phase
        if (kb + 64 < FEAT) {
            const float* px = &x[(size_t)(m0 + r8) * FEAT + (kb + 64) + c8 * 8];
            xa  = *(const float4*)px;
            xb_ = *(const float4*)(px + 4);
        }

        #pragma unroll
        for (int kk = 0; kk < 2; kk++) {
            short8 af[4], bfr[4];
            #pragma unroll
            for (int mt = 0; mt < 4; mt++) {
                int r  = mt * 16 + l15;
                int pc = (kk * 4 + lq) ^ (r & 7);
                af[mt] = *(const short8*)&As[r * 64 + pc * 8];
            }
            #pragma unroll
            for (int nt = 0; nt < 4; nt++) {
                int r  = wave * 64 + nt * 16 + l15;
                int pc = (kk * 4 + lq) ^ (r & 7);
                bfr[nt] = *(const short8*)&Bs[r * 64 + pc * 8];
            }
            #pragma unroll
            for (int mt = 0; mt < 4; mt++)
                #pragma unroll
                for (int nt = 0; nt < 4; nt++)
                    acc[mt][nt] = __builtin_amdgcn_mfma_f32_16x16x32_bf16(
                        af[mt], bfr[nt], acc[mt][nt], 0, 0, 0);
        }
        __syncthreads();
    }

    #pragma unroll
    for (int mt = 0; mt < 4; mt++)
        #pragma unroll
        for (int nt = 0; nt < 4; nt++)
            #pragma unroll
            for (int r = 0; r < 4; r++) {
                int row = m0 + mt * 16 + lq * 4 + r;
                int col = wave * 64 + nt * 16 + l15;
                h[(size_t)row * EMB + col] = f2bf(acc[mt][nt][r]);
            }
}

// ---------------- fallback GEMM (fp32 inputs, in-kernel convert) ----------------
#define BM 128
#define BN 64
#define LDA 72

__global__ __launch_bounds__(256)
void gemm_f32(const float* __restrict__ x, const float* __restrict__ w,
              unsigned short* __restrict__ h)
{
    __shared__ unsigned short As[BM][LDA];
    __shared__ unsigned short Bs[BN][LDA];

    const int t = threadIdx.x, lane = t & 63, wave = t >> 6;
    const int wm = wave >> 1, wn = wave & 1;
    const int l15 = lane & 15, lq = lane >> 4;
    const int xcd = blockIdx.x & 7;
    const int loc = blockIdx.x >> 3;
    const int m0 = (xcd * 64 + (loc >> 3)) * BM;
    const int n0 = (loc & 7) * BN;

    floatx4 acc[4][2];
    #pragma unroll
    for (int i = 0; i < 4; i++)
        #pragma unroll
        for (int j = 0; j < 2; j++) acc[i][j] = (floatx4){0.f, 0.f, 0.f, 0.f};

    for (int kb = 0; kb < FEAT; kb += 64) {
        #pragma unroll
        for (int p = 0; p < 8; p++) {
            int idx = p * 256 + t, row = idx >> 4, cv = (idx & 15) << 2;
            float4 v = *(const float4*)&x[(m0 + row) * FEAT + kb + cv];
            ushort4 b4 = {f2bf(v.x), f2bf(v.y), f2bf(v.z), f2bf(v.w)};
            *(ushort4*)&As[row][cv] = b4;
        }
        #pragma unroll
        for (int p = 0; p < 4; p++) {
            int idx = p * 256 + t, row = idx >> 4, cv = (idx & 15) << 2;
            float4 v = *(const float4*)&w[(n0 + row) * FEAT + kb + cv];
            ushort4 b4 = {f2bf(v.x), f2bf(v.y), f2bf(v.z), f2bf(v.w)};
            *(ushort4*)&Bs[row][cv] = b4;
        }
        __syncthreads();
        #pragma unroll
        for (int kk = 0; kk < 2; kk++) {
            short8 af[4], bf[2];
            #pragma unroll
            for (int mt = 0; mt < 4; mt++)
                af[mt] = *(const short8*)&As[wm * 64 + mt * 16 + l15][kk * 32 + lq * 8];
            #pragma unroll
            for (int nt = 0; nt < 2; nt++)
                bf[nt] = *(const short8*)&Bs[wn * 32 + nt * 16 + l15][kk * 32 + lq * 8];
            #pragma unroll
            for (int mt = 0; mt < 4; mt++)
                #pragma unroll
                for (int nt = 0; nt < 2; nt++)
                    acc[mt][nt] = __builtin_amdgcn_mfma_f32_16x16x32_bf16(
                        af[mt], bf[nt], acc[mt][nt], 0, 0, 0);
        }
        __syncthreads();
    }
    #pragma unroll
    for (int mt = 0; mt < 4; mt++)
        #pragma unroll
        for (int nt = 0; nt < 2; nt++)
            #pragma unroll
            for (int r = 0; r < 4; r++) {
                int row = m0 + wm * 64 + mt * 16 + lq * 4 + r;
                int col = n0 + wn * 32 + nt * 16 + l15;
                h[row * EMB + col] = f2bf(acc[mt][nt][r]);
            }
}

// ---------------- bin edges by destination row (packed 8B payload) ----------------
__global__ __launch_bounds__(256)
void fill_edges(const int* __restrict__ row, const int* __restrict__ col,
                const float* __restrict__ vals, int* __restrict__ cnt,
                uintx2* __restrict__ ebuf)
{
    int e = blockIdx.x * 256 + threadIdx.x;
    int   r = __builtin_nontemporal_load(&row[e]);
    int   c = __builtin_nontemporal_load(&col[e]);
    float v = __builtin_nontemporal_load(&vals[e]);
    int slot = atomicAdd(&cnt[r], 1);
    if (slot < CAP) {
        uintx2 ev; ev.x = (unsigned)c; ev.y = __float_as_uint(v);
        ebuf[r * CAP + slot] = ev;
    }
}

// ---------------- one wave per TWO rows: doubled in-flight gathers (latency probe) ----------------
__global__ __launch_bounds__(256)
void rowsum(const unsigned short* __restrict__ h, const int* __restrict__ cnt,
            const uintx2* __restrict__ ebuf, float* __restrict__ out)
{
    const int wid  = blockIdx.x * 4 + (threadIdx.x >> 6);
    const int rA   = wid * 2;
    const int rB   = rA + 1;
    const int lane = threadIdx.x & 63;

    int dA = cnt[rA]; if (dA > CAP) dA = CAP;
    int dB = cnt[rB]; if (dB > CAP) dB = CAP;

    int cA = 0, cB = 0; float vA = 0.f, vB = 0.f;
    if (lane < dA) { uintx2 e = ebuf[rA * CAP + lane]; cA = (int)e.x; vA = __uint_as_float(e.y); }
    if (lane < dB) { uintx2 e = ebuf[rB * CAP + lane]; cB = (int)e.x; vB = __uint_as_float(e.y); }

    float accA[8] = {0.f,0.f,0.f,0.f,0.f,0.f,0.f,0.f};
    float accB[8] = {0.f,0.f,0.f,0.f,0.f,0.f,0.f,0.f};

    const int dMax  = dA > dB ? dA : dB;
    const int iters = (dMax + 7) >> 3;

    for (int it = 0; it < iters; it++) {
        const int i0 = it * 8;
        uint4 hA[8], hB[8];
        float wA[8], wB[8];
        int nA = dA - i0; if (nA > 8) nA = 8; if (nA < 0) nA = 0;
        int nB = dB - i0; if (nB > 8) nB = 8; if (nB < 0) nB = 0;

        // issue both rows' batches before consuming either (up to 16 gathers in flight)
        #pragma unroll
        for (int j = 0; j < 8; j++) {
            if (j < nA) {
                int c = __shfl(cA, i0 + j, 64);
                wA[j] = __shfl(vA, i0 + j, 64);
                hA[j] = *(const uint4*)&h[(size_t)c * EMB + lane * 8];
            }
        }
        #pragma unroll
        for (int j = 0; j < 8; j++) {
            if (j < nB) {
                int c = __shfl(cB, i0 + j, 64);
                wB[j] = __shfl(vB, i0 + j, 64);
                hB[j] = *(const uint4*)&h[(size_t)c * EMB + lane * 8];
            }
        }
        #pragma unroll
        for (int j = 0; j < 8; j++) {
            if (j < nA) {
                float v = wA[j];
                accA[0] += v * bf2f_lo(hA[j].x); accA[1] += v * bf2f_hi(hA[j].x);
                accA[2] += v * bf2f_lo(hA[j].y); accA[3] += v * bf2f_hi(hA[j].y);
                accA[4] += v * bf2f_lo(hA[j].z); accA[5] += v * bf2f_hi(hA[j].z);
                accA[6] += v * bf2f_lo(hA[j].w); accA[7] += v * bf2f_hi(hA[j].w);
            }
        }
        #pragma unroll
        for (int j = 0; j < 8; j++) {
            if (j < nB) {
                float v = wB[j];
                accB[0] += v * bf2f_lo(hB[j].x); accB[1] += v * bf2f_hi(hB[j].x);
                accB[2] += v * bf2f_lo(hB[j].y); accB[3] += v * bf2f_hi(hB[j].y);
                accB[4] += v * bf2f_lo(hB[j].z); accB[5] += v * bf2f_hi(hB[j].z);
                accB[6] += v * bf2f_lo(hB[j].w); accB[7] += v * bf2f_hi(hB[j].w);
            }
        }
    }

    // non-temporal: out is write-once, never re-read -> don't evict h from L2/L3
    {
        floatx4* o = (floatx4*)&out[(size_t)rA * EMB + lane * 8];
        floatx4 o0; o0.x = accA[0]; o0.y = accA[1]; o0.z = accA[2]; o0.w = accA[3];
        floatx4 o1; o1.x = accA[4]; o1.y = accA[5]; o1.z = accA[6]; o1.w = accA[7];
        __builtin_nontemporal_store(o0, o);
        __builtin_nontemporal_store(o1, o + 1);
    }
    {
        floatx4* o = (floatx4*)&out[(size_t)rB * EMB + lane * 8];
        floatx4 o0; o0.x = accB[0]; o0.y = accB[1]; o0.z = accB[2]; o0.w = accB[3];
        floatx4 o1; o1.x = accB[4]; o1.y = accB[5]; o1.z = accB[6]; o1.w = accB[7];
        __builtin_nontemporal_store(o0, o);
        __builtin_nontemporal_store(o1, o + 1);
    }
}

// ---------------- last-resort: edge-parallel atomic scatter ----------------
__global__ __launch_bounds__(128)
void scatter_atomic(const int* __restrict__ row, const int* __restrict__ col,
                    const float* __restrict__ vals, const unsigned short* __restrict__ h,
                    float* __restrict__ out)
{
    int e = blockIdx.x;
    int r = row[e], c = col[e];
    float v = vals[e];
    int f = threadIdx.x * 4;
    uint2 hv = *(const uint2*)&h[c * EMB + f];
    float* o = &out[r * EMB + f];
    atomicAdd(o + 0, v * bf2f_lo(hv.x));
    atomicAdd(o + 1, v * bf2f_hi(hv.x));
    atomicAdd(o + 2, v * bf2f_lo(hv.y));
    atomicAdd(o + 3, v * bf2f_hi(hv.y));
}

extern "C" void kernel_launch(void* const* d_in, const int* in_sizes, int n_in,
                              void* d_out, int out_size, void* d_ws, size_t ws_size,
                              hipStream_t stream) {
    const float* x    = (const float*)d_in[0];
    const float* w    = (const float*)d_in[1];
    const int*   row  = (const int*)d_in[2];
    const int*   col  = (const int*)d_in[3];
    const float* vals = (const float*)d_in[4];
    float* out = (float*)d_out;
    char* ws = (char*)d_ws;

    const size_t SZ_WB  = (size_t)EMB * FEAT * 2;         //    524,288
    const size_t SZ_H   = (size_t)N_NODES * EMB * 2;      // 67,108,864
    const size_t SZ_CNT = (size_t)N_NODES * 4;            //    262,144
    const size_t SZ_E   = (size_t)N_NODES * CAP * 8;      // 33,554,432 (uintx2 bins)
    const size_t NEED_FAST = SZ_WB + SZ_H + SZ_CNT + SZ_E;    // ~96.9 MB
    const size_t NEED_BIN  = SZ_H + SZ_CNT + SZ_E;            // ~96.4 MB

    if (ws_size >= NEED_FAST) {
        unsigned short* wb = (unsigned short*)ws;
        unsigned short* h  = (unsigned short*)(ws + SZ_WB);
        int*    cnt  = (int*)(ws + SZ_WB + SZ_H);
        uintx2* ebuf = (uintx2*)(ws + SZ_WB + SZ_H + SZ_CNT);

        conv_bf16<<<dim3((EMB * FEAT) / (256 * 8)), dim3(256), 0, stream>>>(w, wb);
        gemm_fused<<<dim3(N_NODES / 64), dim3(512), 0, stream>>>(x, wb, h);
        (void)hipMemsetAsync(cnt, 0, SZ_CNT, stream);
        fill_edges<<<dim3(N_EDGES / 256), dim3(256), 0, stream>>>(row, col, vals, cnt, ebuf);
        rowsum<<<dim3(N_NODES / 8), dim3(256), 0, stream>>>(h, cnt, ebuf, out);
    } else if (ws_size >= NEED_BIN) {
        unsigned short* h = (unsigned short*)ws;
        int*    cnt  = (int*)(ws + SZ_H);
        uintx2* ebuf = (uintx2*)(ws + SZ_H + SZ_CNT);

        gemm_f32<<<dim3(4096), dim3(256), 0, stream>>>(x, w, h);
        (void)hipMemsetAsync(cnt, 0, SZ_CNT, stream);
        fill_edges<<<dim3(N_EDGES / 256), dim3(256), 0, stream>>>(row, col, vals, cnt, ebuf);
        rowsum<<<dim3(N_NODES / 8), dim3(256), 0, stream>>>(h, cnt, ebuf, out);
    } else {
        unsigned short* h = (unsigned short*)ws;
        gemm_f32<<<dim3(4096), dim3(256), 0, stream>>>(x, w, h);
        (void)hipMemsetAsync(out, 0, (size_t)out_size * sizeof(float), stream);
        scatter_atomic<<<dim3(N_EDGES), dim3(128), 0, stream>>>(row, col, vals, h, out);
    }
}

// Round 3
// 388.809 us; speedup vs baseline: 1.0297x; 1.0297x over previous
//
#include <hip/hip_runtime.h>
#include <stdint.h>

// FusedGCNLayer: out = segment_sum(vals * (x @ W^T)[col], row)
// N=65536, E=524288, F=EMB=512.
// Pipeline: (0) convert w fp32->bf16 (tiny)
//           (1) gemm_fused: BM=64 x BN=512 blocks, reg-staged fp32->bf16 A + GLDS B.
//               x is read EXACTLY ONCE from HBM.
//           (2) bin edges by dest row (packed 8B payload); cnt padded to 64B/row
//               to kill atomic cache-line contention at the coherence point.
//           (3) rowsum: one wave per row (32 VGPR, max TLP), gather-accumulate,
//               NT out stores. Split into 2 dispatches for profiling visibility.

#define N_NODES 65536
#define N_EDGES 524288
#define FEAT    512
#define EMB     512
#define CAP     64
#define CNTS    16   // cnt stride in ints (64B line per row counter)

typedef short  short8  __attribute__((ext_vector_type(8)));
typedef float  floatx4 __attribute__((ext_vector_type(4)));
typedef unsigned int uintx2 __attribute__((ext_vector_type(2)));

__device__ __forceinline__ unsigned short f2bf(float f) {
    unsigned int u = __float_as_uint(f);
    u += 0x7FFFu + ((u >> 16) & 1u);   // RNE
    return (unsigned short)(u >> 16);
}
__device__ __forceinline__ float bf2f_lo(unsigned int u){ return __uint_as_float(u << 16); }
__device__ __forceinline__ float bf2f_hi(unsigned int u){ return __uint_as_float(u & 0xffff0000u); }

typedef __attribute__((address_space(1))) const void* gas_vp;
typedef __attribute__((address_space(3))) void*       las_vp;
#define GLDS16(g, l) __builtin_amdgcn_global_load_lds((gas_vp)(const void*)(g), (las_vp)(void*)(l), 16, 0, 0)

// ---------------- fp32 -> bf16 convert (used for w only on fast path) ----------------
__global__ __launch_bounds__(256)
void conv_bf16(const float* __restrict__ in, unsigned short* __restrict__ out)
{
    size_t i = ((size_t)blockIdx.x * 256 + threadIdx.x) * 8;
    floatx4 a = __builtin_nontemporal_load((const floatx4*)&in[i]);
    floatx4 b = __builtin_nontemporal_load((const floatx4*)&in[i + 4]);
    ushort4 lo, hi;
    lo.x = f2bf(a.x); lo.y = f2bf(a.y); lo.z = f2bf(a.z); lo.w = f2bf(a.w);
    hi.x = f2bf(b.x); hi.y = f2bf(b.y); hi.z = f2bf(b.z); hi.w = f2bf(b.w);
    *(ushort4*)&out[i]     = lo;
    *(ushort4*)&out[i + 4] = hi;
}

// ---------------- fused GEMM: BM=64 x BN=512, x read once, in-register convert ----------------
__global__ __launch_bounds__(512, 4)
void gemm_fused(const float* __restrict__ x, const unsigned short* __restrict__ wb,
                unsigned short* __restrict__ h)
{
    __shared__ unsigned short As[64 * 64];    //  8 KB
    __shared__ unsigned short Bs[512 * 64];   // 64 KB

    const int t    = threadIdx.x;      // 0..511
    const int lane = t & 63;
    const int wave = t >> 6;           // 0..7 -> n-block
    const int l15  = lane & 15;
    const int lq   = lane >> 4;

    const int m0 = blockIdx.x * 64;

    const int r8 = t >> 3;             // 0..63 (A row / staging row)
    const int c8 = t & 7;              // 16B chunk index

    floatx4 acc[4][4];
    #pragma unroll
    for (int i = 0; i < 4; i++)
        #pragma unroll
        for (int j = 0; j < 4; j++) acc[i][j] = (floatx4){0.f, 0.f, 0.f, 0.f};

    // prefetch K-step 0 of A into regs
    float4 xa, xb_;
    {
        const float* px = &x[(size_t)(m0 + r8) * FEAT + c8 * 8];
        xa  = *(const float4*)px;
        xb_ = *(const float4*)(px + 4);
    }

    for (int kb = 0; kb < FEAT; kb += 64) {
        // stage Bs: all 512 w-rows, 64-wide K slab, pre-swizzled global source
        #pragma unroll
        for (int p = 0; p < 8; p++) {
            int row = p * 64 + r8;
            int lc  = c8 ^ (r8 & 7);                 // row&7 == r8&7
            GLDS16(&wb[row * FEAT + kb + lc * 8], &Bs[row * 64 + c8 * 8]);
        }
        // convert prefetched A regs -> swizzled LDS write
        {
            short8 v;
            v[0] = (short)f2bf(xa.x);  v[1] = (short)f2bf(xa.y);
            v[2] = (short)f2bf(xa.z);  v[3] = (short)f2bf(xa.w);
            v[4] = (short)f2bf(xb_.x); v[5] = (short)f2bf(xb_.y);
            v[6] = (short)f2bf(xb_.z); v[7] = (short)f2bf(xb_.w);
            *(short8*)&As[r8 * 64 + (c8 ^ (r8 & 7)) * 8] = v;
        }
        __syncthreads();

        // issue next K-step's x loads; latency hides under MFMA phase
        if (kb + 64 < FEAT) {
            const float* px = &x[(size_t)(m0 + r8) * FEAT + (kb + 64) + c8 * 8];
            xa  = *(const float4*)px;
            xb_ = *(const float4*)(px + 4);
        }

        #pragma unroll
        for (int kk = 0; kk < 2; kk++) {
            short8 af[4], bfr[4];
            #pragma unroll
            for (int mt = 0; mt < 4; mt++) {
                int r  = mt * 16 + l15;
                int pc = (kk * 4 + lq) ^ (r & 7);
                af[mt] = *(const short8*)&As[r * 64 + pc * 8];
            }
            #pragma unroll
            for (int nt = 0; nt < 4; nt++) {
                int r  = wave * 64 + nt * 16 + l15;
                int pc = (kk * 4 + lq) ^ (r & 7);
                bfr[nt] = *(const short8*)&Bs[r * 64 + pc * 8];
            }
            #pragma unroll
            for (int mt = 0; mt < 4; mt++)
                #pragma unroll
                for (int nt = 0; nt < 4; nt++)
                    acc[mt][nt] = __builtin_amdgcn_mfma_f32_16x16x32_bf16(
                        af[mt], bfr[nt], acc[mt][nt], 0, 0, 0);
        }
        __syncthreads();
    }

    #pragma unroll
    for (int mt = 0; mt < 4; mt++)
        #pragma unroll
        for (int nt = 0; nt < 4; nt++)
            #pragma unroll
            for (int r = 0; r < 4; r++) {
                int row = m0 + mt * 16 + lq * 4 + r;
                int col = wave * 64 + nt * 16 + l15;
                h[(size_t)row * EMB + col] = f2bf(acc[mt][nt][r]);
            }
}

// ---------------- fallback GEMM (fp32 inputs, in-kernel convert) ----------------
#define BM 128
#define BN 64
#define LDA 72

__global__ __launch_bounds__(256)
void gemm_f32(const float* __restrict__ x, const float* __restrict__ w,
              unsigned short* __restrict__ h)
{
    __shared__ unsigned short As[BM][LDA];
    __shared__ unsigned short Bs[BN][LDA];

    const int t = threadIdx.x, lane = t & 63, wave = t >> 6;
    const int wm = wave >> 1, wn = wave & 1;
    const int l15 = lane & 15, lq = lane >> 4;
    const int xcd = blockIdx.x & 7;
    const int loc = blockIdx.x >> 3;
    const int m0 = (xcd * 64 + (loc >> 3)) * BM;
    const int n0 = (loc & 7) * BN;

    floatx4 acc[4][2];
    #pragma unroll
    for (int i = 0; i < 4; i++)
        #pragma unroll
        for (int j = 0; j < 2; j++) acc[i][j] = (floatx4){0.f, 0.f, 0.f, 0.f};

    for (int kb = 0; kb < FEAT; kb += 64) {
        #pragma unroll
        for (int p = 0; p < 8; p++) {
            int idx = p * 256 + t, row = idx >> 4, cv = (idx & 15) << 2;
            float4 v = *(const float4*)&x[(m0 + row) * FEAT + kb + cv];
            ushort4 b4 = {f2bf(v.x), f2bf(v.y), f2bf(v.z), f2bf(v.w)};
            *(ushort4*)&As[row][cv] = b4;
        }
        #pragma unroll
        for (int p = 0; p < 4; p++) {
            int idx = p * 256 + t, row = idx >> 4, cv = (idx & 15) << 2;
            float4 v = *(const float4*)&w[(n0 + row) * FEAT + kb + cv];
            ushort4 b4 = {f2bf(v.x), f2bf(v.y), f2bf(v.z), f2bf(v.w)};
            *(ushort4*)&Bs[row][cv] = b4;
        }
        __syncthreads();
        #pragma unroll
        for (int kk = 0; kk < 2; kk++) {
            short8 af[4], bf[2];
            #pragma unroll
            for (int mt = 0; mt < 4; mt++)
                af[mt] = *(const short8*)&As[wm * 64 + mt * 16 + l15][kk * 32 + lq * 8];
            #pragma unroll
            for (int nt = 0; nt < 2; nt++)
                bf[nt] = *(const short8*)&Bs[wn * 32 + nt * 16 + l15][kk * 32 + lq * 8];
            #pragma unroll
            for (int mt = 0; mt < 4; mt++)
                #pragma unroll
                for (int nt = 0; nt < 2; nt++)
                    acc[mt][nt] = __builtin_amdgcn_mfma_f32_16x16x32_bf16(
                        af[mt], bf[nt], acc[mt][nt], 0, 0, 0);
        }
        __syncthreads();
    }
    #pragma unroll
    for (int mt = 0; mt < 4; mt++)
        #pragma unroll
        for (int nt = 0; nt < 2; nt++)
            #pragma unroll
            for (int r = 0; r < 4; r++) {
                int row = m0 + wm * 64 + mt * 16 + lq * 4 + r;
                int col = n0 + wn * 32 + nt * 16 + l15;
                h[row * EMB + col] = f2bf(acc[mt][nt][r]);
            }
}

// ---------------- bin edges by destination row (padded counters) ----------------
__global__ __launch_bounds__(256)
void fill_edges(const int* __restrict__ row, const int* __restrict__ col,
                const float* __restrict__ vals, int* __restrict__ cnt,
                uintx2* __restrict__ ebuf)
{
    int e = blockIdx.x * 256 + threadIdx.x;
    int   r = __builtin_nontemporal_load(&row[e]);
    int   c = __builtin_nontemporal_load(&col[e]);
    float v = __builtin_nontemporal_load(&vals[e]);
    int slot = atomicAdd(&cnt[(size_t)r * CNTS], 1);   // 64B/row: no line sharing
    if (slot < CAP) {
        uintx2 ev; ev.x = (unsigned)c; ev.y = __float_as_uint(v);
        ebuf[r * CAP + slot] = ev;
    }
}

// ---------------- one wave per row: batched independent gathers ----------------
__global__ __launch_bounds__(256)
void rowsum(const unsigned short* __restrict__ h, const int* __restrict__ cnt,
            const uintx2* __restrict__ ebuf, float* __restrict__ out, int rbase)
{
    const int r    = rbase + blockIdx.x * 4 + (threadIdx.x >> 6);
    const int lane = threadIdx.x & 63;
    int deg = cnt[(size_t)r * CNTS];
    if (deg > CAP) deg = CAP;
    const int base = r * CAP;

    // lane-parallel 8B packed fetch (wave reads 512B coalesced); broadcast via shuffle
    int   c_l = 0;
    float v_l = 0.f;
    if (lane < deg) {
        uintx2 ev = ebuf[base + lane];
        c_l = (int)ev.x;
        v_l = __uint_as_float(ev.y);
    }

    float acc[8] = {0.f,0.f,0.f,0.f,0.f,0.f,0.f,0.f};
    for (int i0 = 0; i0 < deg; i0 += 8) {
        uint4 hv[8]; float vv[8];
        int nn = deg - i0; if (nn > 8) nn = 8;
        #pragma unroll
        for (int j = 0; j < 8; j++) {
            if (j < nn) {
                int c = __shfl(c_l, i0 + j, 64);
                vv[j] = __shfl(v_l, i0 + j, 64);
                hv[j] = *(const uint4*)&h[(size_t)c * EMB + lane * 8];
            }
        }
        #pragma unroll
        for (int j = 0; j < 8; j++) {
            if (j < nn) {
                float v = vv[j];
                acc[0] += v * bf2f_lo(hv[j].x); acc[1] += v * bf2f_hi(hv[j].x);
                acc[2] += v * bf2f_lo(hv[j].y); acc[3] += v * bf2f_hi(hv[j].y);
                acc[4] += v * bf2f_lo(hv[j].z); acc[5] += v * bf2f_hi(hv[j].z);
                acc[6] += v * bf2f_lo(hv[j].w); acc[7] += v * bf2f_hi(hv[j].w);
            }
        }
    }
    // non-temporal: out is write-once, never re-read -> don't evict h from L2/L3
    floatx4* o = (floatx4*)&out[(size_t)r * EMB + lane * 8];
    floatx4 o0; o0.x = acc[0]; o0.y = acc[1]; o0.z = acc[2]; o0.w = acc[3];
    floatx4 o1; o1.x = acc[4]; o1.y = acc[5]; o1.z = acc[6]; o1.w = acc[7];
    __builtin_nontemporal_store(o0, o);
    __builtin_nontemporal_store(o1, o + 1);
}

// ---------------- last-resort: edge-parallel atomic scatter ----------------
__global__ __launch_bounds__(128)
void scatter_atomic(const int* __restrict__ row, const int* __restrict__ col,
                    const float* __restrict__ vals, const unsigned short* __restrict__ h,
                    float* __restrict__ out)
{
    int e = blockIdx.x;
    int r = row[e], c = col[e];
    float v = vals[e];
    int f = threadIdx.x * 4;
    uint2 hv = *(const uint2*)&h[c * EMB + f];
    float* o = &out[r * EMB + f];
    atomicAdd(o + 0, v * bf2f_lo(hv.x));
    atomicAdd(o + 1, v * bf2f_hi(hv.x));
    atomicAdd(o + 2, v * bf2f_lo(hv.y));
    atomicAdd(o + 3, v * bf2f_hi(hv.y));
}

extern "C" void kernel_launch(void* const* d_in, const int* in_sizes, int n_in,
                              void* d_out, int out_size, void* d_ws, size_t ws_size,
                              hipStream_t stream) {
    const float* x    = (const float*)d_in[0];
    const float* w    = (const float*)d_in[1];
    const int*   row  = (const int*)d_in[2];
    const int*   col  = (const int*)d_in[3];
    const float* vals = (const float*)d_in[4];
    float* out = (float*)d_out;
    char* ws = (char*)d_ws;

    const size_t SZ_WB  = (size_t)EMB * FEAT * 2;           //    524,288
    const size_t SZ_H   = (size_t)N_NODES * EMB * 2;        // 67,108,864
    const size_t SZ_CNT = (size_t)N_NODES * CNTS * 4;       //  4,194,304 (padded)
    const size_t SZ_E   = (size_t)N_NODES * CAP * 8;        // 33,554,432
    const size_t NEED_FAST = SZ_WB + SZ_H + SZ_CNT + SZ_E;  // ~105.4 MB
    const size_t NEED_BIN  = SZ_H + SZ_CNT + SZ_E;          // ~104.9 MB

    if (ws_size >= NEED_FAST) {
        unsigned short* wb = (unsigned short*)ws;
        unsigned short* h  = (unsigned short*)(ws + SZ_WB);
        int*    cnt  = (int*)(ws + SZ_WB + SZ_H);
        uintx2* ebuf = (uintx2*)(ws + SZ_WB + SZ_H + SZ_CNT);

        conv_bf16<<<dim3((EMB * FEAT) / (256 * 8)), dim3(256), 0, stream>>>(w, wb);
        gemm_fused<<<dim3(N_NODES / 64), dim3(512), 0, stream>>>(x, wb, h);
        (void)hipMemsetAsync(cnt, 0, SZ_CNT, stream);
        fill_edges<<<dim3(N_EDGES / 256), dim3(256), 0, stream>>>(row, col, vals, cnt, ebuf);
        rowsum<<<dim3(N_NODES / 8), dim3(256), 0, stream>>>(h, cnt, ebuf, out, 0);
        rowsum<<<dim3(N_NODES / 8), dim3(256), 0, stream>>>(h, cnt, ebuf, out, N_NODES / 2);
    } else if (ws_size >= NEED_BIN) {
        unsigned short* h = (unsigned short*)ws;
        int*    cnt  = (int*)(ws + SZ_H);
        uintx2* ebuf = (uintx2*)(ws + SZ_H + SZ_CNT);

        gemm_f32<<<dim3(4096), dim3(256), 0, stream>>>(x, w, h);
        (void)hipMemsetAsync(cnt, 0, SZ_CNT, stream);
        fill_edges<<<dim3(N_EDGES / 256), dim3(256), 0, stream>>>(row, col, vals, cnt, ebuf);
        rowsum<<<dim3(N_NODES / 8), dim3(256), 0, stream>>>(h, cnt, ebuf, out, 0);
        rowsum<<<dim3(N_NODES / 8), dim3(256), 0, stream>>>(h, cnt, ebuf, out, N_NODES / 2);
    } else {
        unsigned short* h = (unsigned short*)ws;
        gemm_f32<<<dim3(4096), dim3(256), 0, stream>>>(x, w, h);
        (void)hipMemsetAsync(out, 0, (size_t)out_size * sizeof(float), stream);
        scatter_atomic<<<dim3(N_EDGES), dim3(128), 0, stream>>>(row, col, vals, h, out);
    }
}